// Round 8
// baseline (443.142 us; speedup 1.0000x reference)
//
#include <hip/hip_runtime.h>
#include <hip/hip_bf16.h>
#include <math.h>

// Problem constants
#define BB 256
#define TT 512
#define EE 128
#define HH 128
#define NC 4
#define MM (BB * TT)   // 131072 rows of the input GEMM

typedef __bf16 bf16x8 __attribute__((ext_vector_type(8)));
typedef __bf16 bf16x4 __attribute__((ext_vector_type(4)));
typedef float  f32x4  __attribute__((ext_vector_type(4)));

// Branch-free tanh: 1 - 2/(1+e^{2x}) with e^{2x} = exp2(2*log2e*x).
__device__ __forceinline__ float fast_tanh(float x) {
    float t = __builtin_amdgcn_exp2f(x * 2.885390081777927f);
    return 1.f - 2.f * __builtin_amdgcn_rcpf(1.f + t);
}

// Barrier draining ONLY lgkmcnt (LDS), not vmcnt: keeps the xv-ring global
// loads in flight across the barrier (__syncthreads would vmcnt(0)-drain
// them every step [m97 asm evidence]).
__device__ __forceinline__ void bar_lds() {
    asm volatile("s_waitcnt lgkmcnt(0)\n\ts_barrier" ::: "memory");
}

// ---------------------------------------------------------------------------
// Kernel 1 (v3, unchanged from R7): x_proj = gather(emb,x) @ W_ih^T + biases
// ---------------------------------------------------------------------------
template <typename XPT>
__global__ __launch_bounds__(256, 3) void embed_gemm(
    const int* __restrict__ x, const float* __restrict__ emb,
    const float* __restrict__ Wih, const float* __restrict__ bih,
    const float* __restrict__ bhh, XPT* __restrict__ xpout)
{
    const int tid = threadIdx.x;
    const int m0  = blockIdx.x * 64;

    const int LDW = 72;
    const int LDE = 132;
    __shared__ __align__(16) char smem[36864 + 512];
    __bf16* Wh     = (__bf16*)smem;
    __bf16* Wl     = (__bf16*)(smem + 18432);
    float*  epi    = (float*)smem;
    float*  bias_s = (float*)(smem + 36864);

    if (tid < 128) bias_s[tid] = bih[tid] + bhh[tid];

    const int lane = tid & 63, wid = tid >> 6;
    const int col  = lane & 15, quad = lane >> 4;

    const int gi = x[m0 + wid * 16 + col];
    const float* arow = emb + (size_t)gi * 128;

    f32x4 acc[8];
#pragma unroll
    for (int nt = 0; nt < 8; ++nt) acc[nt] = f32x4{0.f, 0.f, 0.f, 0.f};

#pragma unroll
    for (int half = 0; half < 2; ++half) {
#pragma unroll
        for (int it = 0; it < 8; ++it) {
            int c   = it * 256 + tid;
            int row = c >> 4;
            int seg = c & 15;
            float4 wv = ((const float4*)Wih)[row * 32 + half * 16 + seg];
            bf16x4 wh, wl;
            wh[0] = (__bf16)wv.x; wl[0] = (__bf16)(wv.x - (float)wh[0]);
            wh[1] = (__bf16)wv.y; wl[1] = (__bf16)(wv.y - (float)wh[1]);
            wh[2] = (__bf16)wv.z; wl[2] = (__bf16)(wv.z - (float)wh[2]);
            wh[3] = (__bf16)wv.w; wl[3] = (__bf16)(wv.w - (float)wh[3]);
            *(bf16x4*)&Wh[row * LDW + seg * 4] = wh;
            *(bf16x4*)&Wl[row * LDW + seg * 4] = wl;
        }
        __syncthreads();

#pragma unroll
        for (int kk = 0; kk < 2; ++kk) {
            const float* ap = arow + half * 64 + kk * 32 + quad * 8;
            f32x4 a0 = *(const f32x4*)ap;
            f32x4 a1 = *(const f32x4*)(ap + 4);
            bf16x8 afh, afl;
#pragma unroll
            for (int u = 0; u < 4; ++u) {
                afh[u]     = (__bf16)a0[u]; afl[u]     = (__bf16)(a0[u] - (float)afh[u]);
                afh[u + 4] = (__bf16)a1[u]; afl[u + 4] = (__bf16)(a1[u] - (float)afh[u + 4]);
            }
#pragma unroll
            for (int nt = 0; nt < 8; ++nt) {
                int ro = (nt * 16 + col) * LDW + kk * 32 + quad * 8;
                bf16x8 wfh = *(const bf16x8*)&Wh[ro];
                bf16x8 wfl = *(const bf16x8*)&Wl[ro];
                acc[nt] = __builtin_amdgcn_mfma_f32_16x16x32_bf16(afh, wfh, acc[nt], 0, 0, 0);
                acc[nt] = __builtin_amdgcn_mfma_f32_16x16x32_bf16(afl, wfh, acc[nt], 0, 0, 0);
                acc[nt] = __builtin_amdgcn_mfma_f32_16x16x32_bf16(afh, wfl, acc[nt], 0, 0, 0);
            }
        }
        __syncthreads();
    }

#pragma unroll
    for (int nt = 0; nt < 8; ++nt) {
        int n = nt * 16 + col;
        float bs = bias_s[n];
#pragma unroll
        for (int r = 0; r < 4; ++r)
            epi[(wid * 16 + quad * 4 + r) * LDE + n] = acc[nt][r] + bs;
    }
    __syncthreads();

#pragma unroll
    for (int it = 0; it < 8; ++it) {
        int c   = it * 256 + tid;
        int row = c >> 5;
        int cf  = c & 31;
        f32x4 v = *(const f32x4*)&epi[row * LDE + cf * 4];
        if (sizeof(XPT) == 4) {
            *(f32x4*)&((float*)xpout)[(size_t)(m0 + row) * 128 + cf * 4] = v;
        } else {
            bf16x4 bv;
            bv[0] = (__bf16)v[0]; bv[1] = (__bf16)v[1];
            bv[2] = (__bf16)v[2]; bv[3] = (__bf16)v[3];
            *(bf16x4*)&((__bf16*)xpout)[(size_t)(m0 + row) * 128 + cf * 4] = bv;
        }
    }
}

// ---------------------------------------------------------------------------
// Kernel 2: scan + fused MLP head.  h = tanh(x_proj[t] + W_hh @ h), 512 steps.
// ONE lgkmcnt-only barrier per step:
//   phase A (all 4 waves): read OWN wave's h slice from wave-private LDS
//     (written by this same wave last step -> no barrier needed), 64 pk-FMA
//     partials for outputs {lane, lane+64} over K-slice [32q,32q+32),
//     write 2 partials to part[t&1] (ping-pong kills WAR).
//   bar_lds
//   phase B (lanes<32 of each wave): combine 4 partials for output o=32q+l,
//     + xv ring, tanh, write h back to the wave-private slice. The ONLY
//     cross-wave handoff is the partials -> exactly one barrier.
// MLP head fused at the end (hidden=relu(W1 h+b1); logits=W2 hid+b2).
// ---------------------------------------------------------------------------
template <typename XPT>
__global__ __launch_bounds__(256, 1) void rnn_scan_mlp(
    const XPT* __restrict__ xp, const float* __restrict__ Whh,
    const float* __restrict__ h0, const float* __restrict__ W1,
    const float* __restrict__ b1, const float* __restrict__ W2,
    const float* __restrict__ b2, float* __restrict__ out)
{
    const int b    = blockIdx.x;
    const int tid  = threadIdx.x;
    const int q    = tid >> 6;       // wave id = K-slice = owned h slice
    const int lane = tid & 63;
    const int l32  = lane & 31;
    const bool owner = (lane < 32);  // combine lanes
    const int o = q * 32 + l32;      // owned output element (owner lanes)

    __shared__ float h_priv[4][32];     // wave-private h slices
    __shared__ float part[2][4][128];   // ping-pong partials [buf][slice][out]
    __shared__ float h_full[128];
    __shared__ float hid[256];

    // Weights: rows lane and lane+64, K-slice [32q, 32q+32), as float4s.
    f32x4 wA[8], wB[8];
    {
        const float* r0 = Whh + (size_t)lane * 128 + q * 32;
        const float* r1 = Whh + (size_t)(lane + 64) * 128 + q * 32;
#pragma unroll
        for (int c = 0; c < 8; ++c) {
            wA[c] = *(const f32x4*)(r0 + c * 4);
            wB[c] = *(const f32x4*)(r1 + c * 4);
        }
    }
#pragma unroll
    for (int c = 0; c < 8; ++c)
        asm volatile("" : "+v"(wA[c]), "+v"(wB[c]));

    if (owner) h_priv[q][l32] = h0[b * 128 + o];

    // xv ring: owner lane holds xp[b][t][o], 8 steps ahead.
    const XPT* xpb = xp + (size_t)b * (TT * 128);
    float xv[8];
#pragma unroll
    for (int s = 0; s < 8; ++s)
        xv[s] = owner ? (float)xpb[s * 128 + o] : 0.f;

    bar_lds();   // h_priv init visible (within-wave anyway), align all waves

    for (int t = 0; t < TT; ++t) {
        const int p = t & 1;
        // ---- phase A: dot over own slice ----
        const float* hq = &h_priv[q][0];
        f32x4 h4[8];
#pragma unroll
        for (int u = 0; u < 8; ++u) h4[u] = *(const f32x4*)&hq[u * 4];

        f32x4 aA = f32x4{0.f, 0.f, 0.f, 0.f};
        f32x4 aB = f32x4{0.f, 0.f, 0.f, 0.f};
#pragma unroll
        for (int u = 0; u < 8; ++u) {
            aA += wA[u] * h4[u];
            aB += wB[u] * h4[u];
        }
        part[p][q][lane]      = (aA[0] + aA[1]) + (aA[2] + aA[3]);
        part[p][q][64 + lane] = (aB[0] + aB[1]) + (aB[2] + aB[3]);

        bar_lds();   // partials visible to all waves; ONLY barrier per step

        // ---- phase B: combine + tanh in the OWNING wave ----
        if (owner) {
            float s = (part[p][0][o] + part[p][1][o])
                    + (part[p][2][o] + part[p][3][o]);
            float hv = fast_tanh(s + xv[t & 7]);
            h_priv[q][l32] = hv;
            if (t + 8 < TT)
                xv[t & 7] = (float)xpb[(size_t)(t + 8) * 128 + o];
        }
        // next iteration's phase-A read of h_priv[q] is same-wave ordered
        // (lgkmcnt); cross-wave part WAR is handled by the ping-pong.
    }

    // ---- publish final h, then fused MLP head ----
    if (owner) h_full[o] = h_priv[q][l32];
    bar_lds();

    if (tid < 128) out[1024 + b * 128 + tid] = h_full[tid];

    {
        float acc = b1[tid];
        const float4* wrow = (const float4*)(W1 + (size_t)tid * 128);
#pragma unroll
        for (int k4 = 0; k4 < 32; ++k4) {
            float4 wv = wrow[k4];
            acc += wv.x * h_full[k4 * 4 + 0] + wv.y * h_full[k4 * 4 + 1]
                 + wv.z * h_full[k4 * 4 + 2] + wv.w * h_full[k4 * 4 + 3];
        }
        hid[tid] = fmaxf(acc, 0.f);
    }
    __syncthreads();

    float s = 0.f;
#pragma unroll
    for (int qq = 0; qq < 4; ++qq)
        s += hid[qq * 64 + lane] * W2[q * 256 + qq * 64 + lane];
#pragma unroll
    for (int off = 32; off > 0; off >>= 1) s += __shfl_down(s, off);
    if (lane == 0) out[b * 4 + q] = s + b2[q];
}

// ---------------------------------------------------------------------------
extern "C" void kernel_launch(void* const* d_in, const int* in_sizes, int n_in,
                              void* d_out, int out_size, void* d_ws, size_t ws_size,
                              hipStream_t stream)
{
    const int*   x   = (const int*)d_in[0];
    const float* h0  = (const float*)d_in[1];
    const float* emb = (const float*)d_in[2];
    const float* Wih = (const float*)d_in[3];
    const float* Whh = (const float*)d_in[4];
    const float* bih = (const float*)d_in[5];
    const float* bhh = (const float*)d_in[6];
    const float* W1  = (const float*)d_in[7];
    const float* b1  = (const float*)d_in[8];
    const float* W2  = (const float*)d_in[9];
    const float* b2  = (const float*)d_in[10];
    float* out = (float*)d_out;

    const size_t xp_f32_bytes = (size_t)MM * 128 * sizeof(float);   // 64 MB

    if (ws_size >= xp_f32_bytes) {
        float* xpw = (float*)d_ws;
        embed_gemm<float><<<MM / 64, 256, 0, stream>>>(x, emb, Wih, bih, bhh, xpw);
        rnn_scan_mlp<float><<<BB, 256, 0, stream>>>(xpw, Whh, h0, W1, b1, W2, b2, out);
    } else {
        __bf16* xpw = (__bf16*)d_ws;
        embed_gemm<__bf16><<<MM / 64, 256, 0, stream>>>(x, emb, Wih, bih, bhh, xpw);
        rnn_scan_mlp<__bf16><<<BB, 256, 0, stream>>>(xpw, Whh, h0, W1, b1, W2, b2, out);
    }
}

// Round 9
// 285.007 us; speedup vs baseline: 1.5548x; 1.5548x over previous
//
#include <hip/hip_runtime.h>
#include <hip/hip_bf16.h>
#include <math.h>

// Problem constants
#define BB 256
#define TT 512
#define EE 128
#define HH 128
#define NC 4
#define MM (BB * TT)   // 131072 rows of the input GEMM

typedef __bf16 bf16x8 __attribute__((ext_vector_type(8)));
typedef __bf16 bf16x4 __attribute__((ext_vector_type(4)));
typedef float  f32x4  __attribute__((ext_vector_type(4)));

// Branch-free tanh: 1 - 2/(1+e^{2x}) with e^{2x} = exp2(2*log2e*x).
__device__ __forceinline__ float fast_tanh(float x) {
    float t = __builtin_amdgcn_exp2f(x * 2.885390081777927f);
    return 1.f - 2.f * __builtin_amdgcn_rcpf(1.f + t);
}

// Barrier draining ONLY lgkmcnt (LDS), not vmcnt: keeps the xv-ring global
// loads in flight across the barrier (__syncthreads would vmcnt(0)-drain
// them every step [m97 asm evidence]).
__device__ __forceinline__ void bar_lds() {
    asm volatile("s_waitcnt lgkmcnt(0)\n\ts_barrier" ::: "memory");
}

// ---------------------------------------------------------------------------
// Kernel 1 (v3, unchanged from R7): x_proj = gather(emb,x) @ W_ih^T + biases
// ---------------------------------------------------------------------------
template <typename XPT>
__global__ __launch_bounds__(256, 3) void embed_gemm(
    const int* __restrict__ x, const float* __restrict__ emb,
    const float* __restrict__ Wih, const float* __restrict__ bih,
    const float* __restrict__ bhh, XPT* __restrict__ xpout)
{
    const int tid = threadIdx.x;
    const int m0  = blockIdx.x * 64;

    const int LDW = 72;
    const int LDE = 132;
    __shared__ __align__(16) char smem[36864 + 512];
    __bf16* Wh     = (__bf16*)smem;
    __bf16* Wl     = (__bf16*)(smem + 18432);
    float*  epi    = (float*)smem;
    float*  bias_s = (float*)(smem + 36864);

    if (tid < 128) bias_s[tid] = bih[tid] + bhh[tid];

    const int lane = tid & 63, wid = tid >> 6;
    const int col  = lane & 15, quad = lane >> 4;

    const int gi = x[m0 + wid * 16 + col];
    const float* arow = emb + (size_t)gi * 128;

    f32x4 acc[8];
#pragma unroll
    for (int nt = 0; nt < 8; ++nt) acc[nt] = f32x4{0.f, 0.f, 0.f, 0.f};

#pragma unroll
    for (int half = 0; half < 2; ++half) {
#pragma unroll
        for (int it = 0; it < 8; ++it) {
            int c   = it * 256 + tid;
            int row = c >> 4;
            int seg = c & 15;
            float4 wv = ((const float4*)Wih)[row * 32 + half * 16 + seg];
            bf16x4 wh, wl;
            wh[0] = (__bf16)wv.x; wl[0] = (__bf16)(wv.x - (float)wh[0]);
            wh[1] = (__bf16)wv.y; wl[1] = (__bf16)(wv.y - (float)wh[1]);
            wh[2] = (__bf16)wv.z; wl[2] = (__bf16)(wv.z - (float)wh[2]);
            wh[3] = (__bf16)wv.w; wl[3] = (__bf16)(wv.w - (float)wh[3]);
            *(bf16x4*)&Wh[row * LDW + seg * 4] = wh;
            *(bf16x4*)&Wl[row * LDW + seg * 4] = wl;
        }
        __syncthreads();

#pragma unroll
        for (int kk = 0; kk < 2; ++kk) {
            const float* ap = arow + half * 64 + kk * 32 + quad * 8;
            f32x4 a0 = *(const f32x4*)ap;
            f32x4 a1 = *(const f32x4*)(ap + 4);
            bf16x8 afh, afl;
#pragma unroll
            for (int u = 0; u < 4; ++u) {
                afh[u]     = (__bf16)a0[u]; afl[u]     = (__bf16)(a0[u] - (float)afh[u]);
                afh[u + 4] = (__bf16)a1[u]; afl[u + 4] = (__bf16)(a1[u] - (float)afh[u + 4]);
            }
#pragma unroll
            for (int nt = 0; nt < 8; ++nt) {
                int ro = (nt * 16 + col) * LDW + kk * 32 + quad * 8;
                bf16x8 wfh = *(const bf16x8*)&Wh[ro];
                bf16x8 wfl = *(const bf16x8*)&Wl[ro];
                acc[nt] = __builtin_amdgcn_mfma_f32_16x16x32_bf16(afh, wfh, acc[nt], 0, 0, 0);
                acc[nt] = __builtin_amdgcn_mfma_f32_16x16x32_bf16(afl, wfh, acc[nt], 0, 0, 0);
                acc[nt] = __builtin_amdgcn_mfma_f32_16x16x32_bf16(afh, wfl, acc[nt], 0, 0, 0);
            }
        }
        __syncthreads();
    }

#pragma unroll
    for (int nt = 0; nt < 8; ++nt) {
        int n = nt * 16 + col;
        float bs = bias_s[n];
#pragma unroll
        for (int r = 0; r < 4; ++r)
            epi[(wid * 16 + quad * 4 + r) * LDE + n] = acc[nt][r] + bs;
    }
    __syncthreads();

#pragma unroll
    for (int it = 0; it < 8; ++it) {
        int c   = it * 256 + tid;
        int row = c >> 5;
        int cf  = c & 31;
        f32x4 v = *(const f32x4*)&epi[row * LDE + cf * 4];
        if (sizeof(XPT) == 4) {
            *(f32x4*)&((float*)xpout)[(size_t)(m0 + row) * 128 + cf * 4] = v;
        } else {
            bf16x4 bv;
            bv[0] = (__bf16)v[0]; bv[1] = (__bf16)v[1];
            bv[2] = (__bf16)v[2]; bv[3] = (__bf16)v[3];
            *(bf16x4*)&((__bf16*)xpout)[(size_t)(m0 + row) * 128 + cf * 4] = bv;
        }
    }
}

// ---------------------------------------------------------------------------
// Kernel 2: scan + fused MLP head, ONE lgkmcnt-only barrier per step.
// R9 fix vs R8: the t-loop is an 8-unrolled window again, so the xv ring is
// STATIC-indexed -> stays in VGPRs. (R8's flat loop made xv[t&7] dynamic ->
// scratch-allocated -> ~800 extra cycles/step on the serial path;
// VGPR_Count=64 was the tell.)
//   phase A (all 4 waves): dot over OWN wave's h slice (wave-private LDS,
//     same-wave ordering, no barrier) -> 2 partials into part[ts&1].
//   bar_lds (the only barrier)
//   phase B (lanes<32): combine 4 partials for output o=32q+l32, + xv,
//     tanh, write h back to the wave-private slice, refill xv[ts].
// MLP head fused at the end.
// ---------------------------------------------------------------------------
template <typename XPT>
__global__ __launch_bounds__(256, 1) void rnn_scan_mlp(
    const XPT* __restrict__ xp, const float* __restrict__ Whh,
    const float* __restrict__ h0, const float* __restrict__ W1,
    const float* __restrict__ b1, const float* __restrict__ W2,
    const float* __restrict__ b2, float* __restrict__ out)
{
    const int b    = blockIdx.x;
    const int tid  = threadIdx.x;
    const int q    = tid >> 6;       // wave id = K-slice = owned h slice
    const int lane = tid & 63;
    const int l32  = lane & 31;
    const bool owner = (lane < 32);  // combine lanes
    const int o = q * 32 + l32;      // owned output element (owner lanes)

    __shared__ float h_priv[4][32];     // wave-private h slices
    __shared__ float part[2][4][128];   // ping-pong partials [buf][slice][out]
    __shared__ float h_full[128];
    __shared__ float hid[256];

    // Weights: rows lane and lane+64, K-slice [32q, 32q+32), as float4s.
    f32x4 wA[8], wB[8];
    {
        const float* r0 = Whh + (size_t)lane * 128 + q * 32;
        const float* r1 = Whh + (size_t)(lane + 64) * 128 + q * 32;
#pragma unroll
        for (int c = 0; c < 8; ++c) {
            wA[c] = *(const f32x4*)(r0 + c * 4);
            wB[c] = *(const f32x4*)(r1 + c * 4);
        }
    }
#pragma unroll
    for (int c = 0; c < 8; ++c)
        asm volatile("" : "+v"(wA[c]), "+v"(wB[c]));

    if (owner) h_priv[q][l32] = h0[b * 128 + o];

    // xv ring: owner lane holds xp[b][t][o], 8 steps ahead (STATIC indexing).
    const XPT* xpb = xp + (size_t)b * (TT * 128);
    float xv[8];
#pragma unroll
    for (int s = 0; s < 8; ++s)
        xv[s] = owner ? (float)xpb[s * 128 + o] : 0.f;

    bar_lds();   // h_priv init visible across waves' phase-A reads? (own only) — aligns waves

    for (int tw = 0; tw < TT; tw += 8) {
#pragma unroll
        for (int ts = 0; ts < 8; ++ts) {
            const int p = ts & 1;   // (tw+ts)&1 == ts&1 since tw % 8 == 0
            // ---- phase A: dot over own slice ----
            const float* hq = &h_priv[q][0];
            f32x4 h4[8];
#pragma unroll
            for (int u = 0; u < 8; ++u) h4[u] = *(const f32x4*)&hq[u * 4];

            f32x4 aA = f32x4{0.f, 0.f, 0.f, 0.f};
            f32x4 aB = f32x4{0.f, 0.f, 0.f, 0.f};
#pragma unroll
            for (int u = 0; u < 8; ++u) {
                aA += wA[u] * h4[u];
                aB += wB[u] * h4[u];
            }
            part[p][q][lane]      = (aA[0] + aA[1]) + (aA[2] + aA[3]);
            part[p][q][64 + lane] = (aB[0] + aB[1]) + (aB[2] + aB[3]);

            bar_lds();   // partials visible; ONLY barrier per step

            // ---- phase B: combine + tanh in the OWNING wave ----
            if (owner) {
                float s = (part[p][0][o] + part[p][1][o])
                        + (part[p][2][o] + part[p][3][o]);
                float hv = fast_tanh(s + xv[ts]);
                h_priv[q][l32] = hv;
                if (tw + 8 < TT)
                    xv[ts] = (float)xpb[(size_t)(tw + 8 + ts) * 128 + o];
            }
            // next phase-A read of h_priv[q] is same-wave lgkmcnt-ordered;
            // cross-wave part WAR handled by the ping-pong buffers.
        }
    }

    // ---- publish final h, then fused MLP head ----
    if (owner) h_full[o] = h_priv[q][l32];
    bar_lds();

    if (tid < 128) out[1024 + b * 128 + tid] = h_full[tid];

    {
        float acc = b1[tid];
        const float4* wrow = (const float4*)(W1 + (size_t)tid * 128);
#pragma unroll
        for (int k4 = 0; k4 < 32; ++k4) {
            float4 wv = wrow[k4];
            acc += wv.x * h_full[k4 * 4 + 0] + wv.y * h_full[k4 * 4 + 1]
                 + wv.z * h_full[k4 * 4 + 2] + wv.w * h_full[k4 * 4 + 3];
        }
        hid[tid] = fmaxf(acc, 0.f);
    }
    __syncthreads();

    float s = 0.f;
#pragma unroll
    for (int qq = 0; qq < 4; ++qq)
        s += hid[qq * 64 + lane] * W2[q * 256 + qq * 64 + lane];
#pragma unroll
    for (int off = 32; off > 0; off >>= 1) s += __shfl_down(s, off);
    if (lane == 0) out[b * 4 + q] = s + b2[q];
}

// ---------------------------------------------------------------------------
extern "C" void kernel_launch(void* const* d_in, const int* in_sizes, int n_in,
                              void* d_out, int out_size, void* d_ws, size_t ws_size,
                              hipStream_t stream)
{
    const int*   x   = (const int*)d_in[0];
    const float* h0  = (const float*)d_in[1];
    const float* emb = (const float*)d_in[2];
    const float* Wih = (const float*)d_in[3];
    const float* Whh = (const float*)d_in[4];
    const float* bih = (const float*)d_in[5];
    const float* bhh = (const float*)d_in[6];
    const float* W1  = (const float*)d_in[7];
    const float* b1  = (const float*)d_in[8];
    const float* W2  = (const float*)d_in[9];
    const float* b2  = (const float*)d_in[10];
    float* out = (float*)d_out;

    const size_t xp_f32_bytes = (size_t)MM * 128 * sizeof(float);   // 64 MB

    if (ws_size >= xp_f32_bytes) {
        float* xpw = (float*)d_ws;
        embed_gemm<float><<<MM / 64, 256, 0, stream>>>(x, emb, Wih, bih, bhh, xpw);
        rnn_scan_mlp<float><<<BB, 256, 0, stream>>>(xpw, Whh, h0, W1, b1, W2, b2, out);
    } else {
        __bf16* xpw = (__bf16*)d_ws;
        embed_gemm<__bf16><<<MM / 64, 256, 0, stream>>>(x, emb, Wih, bih, bhh, xpw);
        rnn_scan_mlp<__bf16><<<BB, 256, 0, stream>>>(xpw, Whh, h0, W1, b1, W2, b2, out);
    }
}